// Round 3
// baseline (5480.699 us; speedup 1.0000x reference)
//
#include <hip/hip_runtime.h>
#include <stdint.h>

#define BATCH 256
#define SEQ   512
#define INDIM 64
#define HID   512

typedef _Float16 half2_t __attribute__((ext_vector_type(2)));

__device__ __forceinline__ float dot2f(uint32_t w, uint32_t h, float acc) {
    return __builtin_amdgcn_fdot2(__builtin_bit_cast(half2_t, w),
                                  __builtin_bit_cast(half2_t, h), acc, false);
}
__device__ __forceinline__ uint32_t pack2(float a, float b) {
    half2_t h; h[0] = (_Float16)a; h[1] = (_Float16)b;
    return __builtin_bit_cast(uint32_t, h);
}
// partner-exchange-and-add via DPP quad_perm; 0xB1 = xor1, 0x4E = xor2
template<int CTRL>
__device__ __forceinline__ float dpp_sum(float x) {
    int xi = __builtin_bit_cast(int, x);
    int yi = __builtin_amdgcn_mov_dpp(xi, CTRL, 0xF, 0xF, true);
    return x + __builtin_bit_cast(float, yi);
}

#define SLICE_PAD 136   // 128 + 8 f16 pad: slice streams land 4 banks apart

struct Smem {
    _Float16 h[2][4 * SLICE_PAD];   // double-buffered hidden state
    _Float16 xb[2][INDIM];          // double-buffered x_t (f16)
};

__global__ __launch_bounds__(1024, 4)
void rnn_k4_kernel(const float* __restrict__ x, const float* __restrict__ h0,
                   const float* __restrict__ W_ih, const float* __restrict__ W_hh,
                   const float* __restrict__ b_ih, const float* __restrict__ b_hh,
                   float* __restrict__ out)
{
    __shared__ Smem sm;
    const int t = threadIdx.x;
    const int b = blockIdx.x;
    const int s  = t & 3;          // k-slice: k in [s*128, s*128+128)
    const int q  = t >> 2;         // quad id: rows 2q, 2q+1
    const int r0 = 2 * q, r1 = r0 + 1;

    // ---- W_hh rows r0,r1 (k-slice s) fully in registers: 128 packed ----
    uint32_t w0[64], w1[64];
    {
        const float* wr0 = W_hh + (size_t)r0 * HID + s * 128;
        const float* wr1 = W_hh + (size_t)r1 * HID + s * 128;
        #pragma unroll
        for (int c = 0; c < 32; ++c) {
            float4 v = ((const float4*)wr0)[c];
            w0[2*c] = pack2(v.x, v.y); w0[2*c+1] = pack2(v.z, v.w);
        }
        #pragma unroll
        for (int c = 0; c < 32; ++c) {
            float4 v = ((const float4*)wr1)[c];
            w1[2*c] = pack2(v.x, v.y); w1[2*c+1] = pack2(v.z, v.w);
        }
    }
    // ---- W_ih rows r0,r1, input slice [16s, 16s+16): 16 packed ----
    uint32_t wi0[8], wi1[8];
    {
        const float* p0 = W_ih + (size_t)r0 * INDIM + s * 16;
        const float* p1 = W_ih + (size_t)r1 * INDIM + s * 16;
        #pragma unroll
        for (int c = 0; c < 4; ++c) {
            float4 v = ((const float4*)p0)[c];
            wi0[2*c] = pack2(v.x, v.y); wi0[2*c+1] = pack2(v.z, v.w);
            float4 u = ((const float4*)p1)[c];
            wi1[2*c] = pack2(u.x, u.y); wi1[2*c+1] = pack2(u.z, u.w);
        }
    }
    const float bs0 = b_ih[r0] + b_hh[r0];
    const float bs1 = b_ih[r1] + b_hh[r1];

    if (t < HID)
        sm.h[0][(t >> 7) * SLICE_PAD + (t & 127)] = (_Float16)h0[(size_t)b * HID + t];
    const float* xrow = x + (size_t)b * SEQ * INDIM;
    if (t < INDIM) sm.xb[0][t] = (_Float16)xrow[t];
    __syncthreads();

    float hl0 = 0.f, hl1 = 0.f;
    #pragma unroll 1
    for (int tt = 0; tt < SEQ; ++tt) {
        const int par = tt & 1;

        // prefetch next x_t (wave 0 only; latency hidden under the dots)
        float xnext = 0.f;
        if (t < INDIM && tt + 1 < SEQ) xnext = xrow[(size_t)(tt + 1) * INDIM + t];

        const uint4* hp = (const uint4*)&sm.h[par][s * SLICE_PAD];
        float a0 = 0.f, a1 = 0.f, a2 = 0.f, a3 = 0.f;  // a0/a2: row0, a1/a3: row1

        #pragma unroll
        for (int c = 0; c < 16; ++c) {
            uint4 hc = hp[c];                    // 8 f16 of h, this k-slice
            if ((c & 1) == 0) {
                a0 = dot2f(w0[4*c+0], hc.x, a0); a0 = dot2f(w0[4*c+1], hc.y, a0);
                a0 = dot2f(w0[4*c+2], hc.z, a0); a0 = dot2f(w0[4*c+3], hc.w, a0);
                a1 = dot2f(w1[4*c+0], hc.x, a1); a1 = dot2f(w1[4*c+1], hc.y, a1);
                a1 = dot2f(w1[4*c+2], hc.z, a1); a1 = dot2f(w1[4*c+3], hc.w, a1);
            } else {
                a2 = dot2f(w0[4*c+0], hc.x, a2); a2 = dot2f(w0[4*c+1], hc.y, a2);
                a2 = dot2f(w0[4*c+2], hc.z, a2); a2 = dot2f(w0[4*c+3], hc.w, a2);
                a3 = dot2f(w1[4*c+0], hc.x, a3); a3 = dot2f(w1[4*c+1], hc.y, a3);
                a3 = dot2f(w1[4*c+2], hc.z, a3); a3 = dot2f(w1[4*c+3], hc.w, a3);
            }
        }

        // x-projection, input slice [16s,16s+16)
        {
            const uint4* xp = (const uint4*)&sm.xb[par][s * 16];
            uint4 xc = xp[0], xd = xp[1];
            a0 = dot2f(wi0[0], xc.x, a0); a0 = dot2f(wi0[1], xc.y, a0);
            a0 = dot2f(wi0[2], xc.z, a0); a0 = dot2f(wi0[3], xc.w, a0);
            a2 = dot2f(wi0[4], xd.x, a2); a2 = dot2f(wi0[5], xd.y, a2);
            a2 = dot2f(wi0[6], xd.z, a2); a2 = dot2f(wi0[7], xd.w, a2);
            a1 = dot2f(wi1[0], xc.x, a1); a1 = dot2f(wi1[1], xc.y, a1);
            a1 = dot2f(wi1[2], xc.z, a1); a1 = dot2f(wi1[3], xc.w, a1);
            a3 = dot2f(wi1[4], xd.x, a3); a3 = dot2f(wi1[5], xd.y, a3);
            a3 = dot2f(wi1[6], xd.z, a3); a3 = dot2f(wi1[7], xd.w, a3);
        }

        // quad-wide k-reduction: 2 DPP rounds, all lanes end with the full sum
        float f0 = a0 + a2;
        float f1 = a1 + a3;
        f0 = dpp_sum<0xB1>(f0); f0 = dpp_sum<0x4E>(f0);
        f1 = dpp_sum<0xB1>(f1); f1 = dpp_sum<0x4E>(f1);
        f0 += bs0; f1 += bs1;

        // fast tanh: 1 - 2/(e^{2x}+1), saturates correctly
        float e0 = __expf(2.0f * f0);
        float th0 = 1.0f - 2.0f * __builtin_amdgcn_rcpf(e0 + 1.0f);
        float e1 = __expf(2.0f * f1);
        float th1 = 1.0f - 2.0f * __builtin_amdgcn_rcpf(e1 + 1.0f);

        if (s == 0) sm.h[1 - par][(r0 >> 7) * SLICE_PAD + (r0 & 127)] = (_Float16)th0;
        if (s == 1) sm.h[1 - par][(r1 >> 7) * SLICE_PAD + (r1 & 127)] = (_Float16)th1;
        if (t < INDIM && tt + 1 < SEQ) sm.xb[1 - par][t] = (_Float16)xnext;

        hl0 = th0; hl1 = th1;
        __syncthreads();
    }

    // outputs: (last_step_features, h_n) — both equal final h
    const size_t oA = (size_t)b * HID;
    const size_t oB = (size_t)BATCH * HID + oA;
    if (s == 0)      { out[oA + r0] = hl0; out[oA + r1] = hl1; }
    else if (s == 1) { out[oB + r0] = hl0; out[oB + r1] = hl1; }
}

extern "C" void kernel_launch(void* const* d_in, const int* in_sizes, int n_in,
                              void* d_out, int out_size, void* d_ws, size_t ws_size,
                              hipStream_t stream) {
    (void)in_sizes; (void)n_in; (void)out_size; (void)d_ws; (void)ws_size;
    const float* x    = (const float*)d_in[0];
    const float* h0   = (const float*)d_in[1];
    const float* W_ih = (const float*)d_in[2];
    const float* W_hh = (const float*)d_in[3];
    const float* b_ih = (const float*)d_in[4];
    const float* b_hh = (const float*)d_in[5];
    float* out = (float*)d_out;

    hipLaunchKernelGGL(rnn_k4_kernel, dim3(BATCH), dim3(1024), 0, stream,
                       x, h0, W_ih, W_hh, b_ih, b_hh, out);
}

// Round 5
// 2628.059 us; speedup vs baseline: 2.0855x; 2.0855x over previous
//
#include <hip/hip_runtime.h>
#include <stdint.h>

#define BATCH 256
#define SEQ   512
#define INDIM 64
#define HID   512

typedef _Float16 f16;
typedef _Float16 f16x2 __attribute__((ext_vector_type(2)));
typedef _Float16 f16x8 __attribute__((ext_vector_type(8)));
typedef float    f32x4 __attribute__((ext_vector_type(4)));

#define XP_BYTES  134217728ULL  // 16 blk * 512 s * 32 tiles * 64 lanes * 4 f16 * 2B
#define WSC_BYTES 65536ULL      // 2 kappa * 32 tiles * 64 lanes * 16B
#define WS_NEED   (XP_BYTES + WSC_BYTES)

// Row permutation making D-layout -> next-step B-frag conversion lane-local.
__device__ __forceinline__ int row_of(int wv, int rho, int m) {
    return wv*128 + (rho>>1)*32 + (m>>2)*8 + (rho&1)*4 + (m&3);
}
__device__ __forceinline__ f16x2 pkrtz(float a, float b) {
    return __builtin_bit_cast(f16x2, __builtin_amdgcn_cvt_pkrtz(a, b));
}
union FU { f16x8 v; f16x2 h2[4]; uint32_t u[4]; };
__device__ __forceinline__ f16x8 pack8(float4 a, float4 b) {
    FU r;
    r.h2[0] = pkrtz(a.x, a.y); r.h2[1] = pkrtz(a.z, a.w);
    r.h2[2] = pkrtz(b.x, b.y); r.h2[3] = pkrtz(b.z, b.w);
    return r.v;
}
__device__ __forceinline__ float fast_tanh(float x) {
    float e = __expf(2.0f * x);
    return 1.0f - 2.0f * __builtin_amdgcn_rcpf(e + 1.0f);
}
__device__ __forceinline__ f32x4 mfma16(f16x8 a, f16x8 b, f32x4 c) {
    return __builtin_amdgcn_mfma_f32_16x16x32_f16(a, b, c, 0, 0, 0);
}

// ---- sidecar: W_hh kappa=14,15 as f16 frags (read from L2 each step) ----
__global__ void wconv_kernel(const float* __restrict__ W_hh, f16* __restrict__ wsc)
{
    int id = blockIdx.x * 256 + threadIdx.x;          // 0 .. 4095
    if (id >= 2*32*64) return;
    int l = id & 63, tile = (id >> 6) & 31, ks = id >> 11;
    int wv = tile >> 3, rho = tile & 7, g = l >> 4, c = l & 15;
    const float* p = W_hh + (size_t)row_of(wv, rho, c) * HID + (14 + ks) * 32 + g * 8;
    f16x8 v = pack8(((const float4*)p)[0], ((const float4*)p)[1]);
    *(f16x8*)(wsc + (size_t)id * 8) = v;
}

// ---- xp = x @ W_ih^T + b_ih + b_hh, stored f16 in D-frag layout ----
__global__ __launch_bounds__(256)
void xp_gemm_kernel(const float* __restrict__ x, const float* __restrict__ W_ih,
                    const float* __restrict__ b_ih, const float* __restrict__ b_hh,
                    f16* __restrict__ xp)
{
    const int t = threadIdx.x, wv = t >> 6, l = t & 63, g = l >> 4, c = l & 15;
    const int bb = blockIdx.x;          // batch block 0..15
    const int sc = blockIdx.y;          // s chunk 0..15 (32 s each)

    f16x8 wf[8][2];
    #pragma unroll
    for (int rho = 0; rho < 8; ++rho) {
        const float* pr = W_ih + (size_t)row_of(wv, rho, c) * INDIM;
        #pragma unroll
        for (int kx = 0; kx < 2; ++kx) {
            const float* p4 = pr + kx * 32 + g * 8;
            wf[rho][kx] = pack8(((const float4*)p4)[0], ((const float4*)p4)[1]);
        }
    }
    float bias[8][4];
    #pragma unroll
    for (int rho = 0; rho < 8; ++rho)
        #pragma unroll
        for (int r = 0; r < 4; ++r) {
            int row = row_of(wv, rho, 4 * g + r);
            bias[rho][r] = b_ih[row] + b_hh[row];
        }

    const float* xb = x + (size_t)(bb * 16 + c) * SEQ * INDIM;
    #pragma unroll 1
    for (int si = 0; si < 32; ++si) {
        const int s = sc * 32 + si;
        const float* xs = xb + (size_t)s * INDIM;
        f16x8 bx[2];
        #pragma unroll
        for (int kx = 0; kx < 2; ++kx) {
            const float* p4 = xs + kx * 32 + g * 8;
            bx[kx] = pack8(((const float4*)p4)[0], ((const float4*)p4)[1]);
        }
        #pragma unroll
        for (int rho = 0; rho < 8; ++rho) {
            f32x4 acc; acc[0] = bias[rho][0]; acc[1] = bias[rho][1];
            acc[2] = bias[rho][2]; acc[3] = bias[rho][3];
            acc = mfma16(wf[rho][0], bx[0], acc);
            acc = mfma16(wf[rho][1], bx[1], acc);
            f16x2 lo = pkrtz(acc[0], acc[1]), hi = pkrtz(acc[2], acc[3]);
            uint2 st;
            st.x = __builtin_bit_cast(uint32_t, lo);
            st.y = __builtin_bit_cast(uint32_t, hi);
            size_t idx = (((size_t)bb * SEQ + s) * 32 + wv * 8 + rho) * 64 + l;
            *(uint2*)(xp + idx * 4) = st;
        }
    }
}

// ---- persistent recurrent kernel: 16 blocks x 256 thr, batch 16 per block ----
__global__ __launch_bounds__(256, 1)
void rnn_mfma_kernel(const float* __restrict__ h0, const float* __restrict__ W_hh,
                     const f16* __restrict__ xp, const f16* __restrict__ wsc,
                     float* __restrict__ out)
{
    __shared__ f16x8 s_wlds[3 * 32 * 64];   // kappa 11..13 frags, 96 KB
    __shared__ f16x8 s_hbuf[2 * 16 * 64];   // h frag double buffer, 32 KB
    const int t = threadIdx.x, wv = t >> 6, l = t & 63, g = l >> 4, c = l & 15;
    const int bb = blockIdx.x;

    // W_hh kappa 0..10 into registers (A-frag layout, permuted rows)
    f16x8 wreg[11][8];
    #pragma unroll
    for (int kk = 0; kk < 11; ++kk)
        #pragma unroll
        for (int rho = 0; rho < 8; ++rho) {
            const float* p4 = W_hh + (size_t)row_of(wv, rho, c) * HID + kk * 32 + g * 8;
            wreg[kk][rho] = pack8(((const float4*)p4)[0], ((const float4*)p4)[1]);
        }
    // W_hh kappa 11..13 into LDS
    #pragma unroll
    for (int kk = 0; kk < 3; ++kk)
        #pragma unroll
        for (int rho = 0; rho < 8; ++rho) {
            const float* p4 = W_hh + (size_t)row_of(wv, rho, c) * HID + (11 + kk) * 32 + g * 8;
            s_wlds[(kk * 32 + wv * 8 + rho) * 64 + l] =
                pack8(((const float4*)p4)[0], ((const float4*)p4)[1]);
        }
    // h0 frags (own kappa range [4wv, 4wv+4))
    f16x8 ownf[4];
    #pragma unroll
    for (int P = 0; P < 4; ++P) {
        const float* p4 = h0 + (size_t)(bb * 16 + c) * HID + (4 * wv + P) * 32 + g * 8;
        ownf[P] = pack8(((const float4*)p4)[0], ((const float4*)p4)[1]);
        s_hbuf[(4 * wv + P) * 64 + l] = ownf[P];
    }

    const f16* xpb = xp + ((size_t)bb * SEQ * 32 + wv * 8) * 256;
    uint2 xn[8];
    #pragma unroll
    for (int rho = 0; rho < 8; ++rho)
        xn[rho] = *(const uint2*)(xpb + rho * 256 + l * 4);

    const f16x8* wsb = (const f16x8*)wsc;
    __syncthreads();

    int p = 0;
    #pragma unroll 1
    for (int tt = 0; tt < SEQ; ++tt) {
        // issue streamed-W kappa14 early (consumed mid-loop)
        f16x8 sfA[8];
        #pragma unroll
        for (int rho = 0; rho < 8; ++rho)
            sfA[rho] = wsb[(0 * 32 + wv * 8 + rho) * 64 + l];

        // C-init from xp (f16 -> f32), then prefetch next step's xp
        f32x4 acc[8];
        #pragma unroll
        for (int rho = 0; rho < 8; ++rho) {
            f16x2 lo = __builtin_bit_cast(f16x2, xn[rho].x);
            f16x2 hi = __builtin_bit_cast(f16x2, xn[rho].y);
            f32x4 a; a[0] = (float)lo[0]; a[1] = (float)lo[1];
            a[2] = (float)hi[0]; a[3] = (float)hi[1];
            acc[rho] = a;
        }
        if (tt + 1 < SEQ) {
            const f16* xq = xpb + (size_t)(tt + 1) * 8192;
            #pragma unroll
            for (int rho = 0; rho < 8; ++rho)
                xn[rho] = *(const uint2*)(xq + rho * 256 + l * 4);
        }
        const f16x8* hb = s_hbuf + p * 1024;

        #define BFR(KAP) \
            f16x8 bf; if (((KAP) >> 2) == wv) bf = ownf[(KAP) & 3]; \
            else bf = hb[(KAP) * 64 + l];
        #define DOR(KK, KAP) { BFR(KAP); \
            _Pragma("unroll") for (int rho = 0; rho < 8; ++rho) \
                acc[rho] = mfma16(wreg[KK][rho], bf, acc[rho]); }
        #define DOS(SF, KAP) { BFR(KAP); \
            _Pragma("unroll") for (int rho = 0; rho < 8; ++rho) \
                acc[rho] = mfma16(SF[rho], bf, acc[rho]); }
        #define DOL(KKL, KAP) { BFR(KAP); \
            _Pragma("unroll") for (int rho = 0; rho < 8; ++rho) \
                acc[rho] = mfma16(s_wlds[((KKL) * 32 + wv * 8 + rho) * 64 + l], bf, acc[rho]); }

        DOR(0, 0); DOR(1, 1); DOR(2, 2); DOR(3, 3); DOR(4, 4); DOR(5, 5);
        f16x8 sfB[8];
        #pragma unroll
        for (int rho = 0; rho < 8; ++rho)
            sfB[rho] = wsb[(1 * 32 + wv * 8 + rho) * 64 + l];
        DOS(sfA, 14);
        DOR(6, 6); DOR(7, 7); DOR(8, 8); DOR(9, 9); DOR(10, 10);
        DOS(sfB, 15);
        DOL(0, 11); DOL(1, 12); DOL(2, 13);

        // tanh -> pack (lane-local, thanks to row permutation) -> LDS + own frags
        f16x8* hw = s_hbuf + (1 - p) * 1024;
        #pragma unroll
        for (int P = 0; P < 4; ++P) {
            float t0 = fast_tanh(acc[2*P][0]),   t1 = fast_tanh(acc[2*P][1]);
            float t2 = fast_tanh(acc[2*P][2]),   t3 = fast_tanh(acc[2*P][3]);
            float t4 = fast_tanh(acc[2*P+1][0]), t5 = fast_tanh(acc[2*P+1][1]);
            float t6 = fast_tanh(acc[2*P+1][2]), t7 = fast_tanh(acc[2*P+1][3]);
            FU fu;
            fu.h2[0] = pkrtz(t0, t1); fu.h2[1] = pkrtz(t2, t3);
            fu.h2[2] = pkrtz(t4, t5); fu.h2[3] = pkrtz(t6, t7);
            ownf[P] = fu.v;
            hw[(4 * wv + P) * 64 + l] = fu.v;
            if (tt == SEQ - 1) {
                float* ob = out + (size_t)(bb * 16 + c) * HID;
                float* o2 = ob + (size_t)BATCH * HID;
                int ra = row_of(wv, 2 * P, 4 * g);      // rows ra..ra+3 = t0..t3
                int rb = row_of(wv, 2 * P + 1, 4 * g);  // rows rb..rb+3 = t4..t7
                ob[ra + 0] = t0; ob[ra + 1] = t1; ob[ra + 2] = t2; ob[ra + 3] = t3;
                ob[rb + 0] = t4; ob[rb + 1] = t5; ob[rb + 2] = t6; ob[rb + 3] = t7;
                o2[ra + 0] = t0; o2[ra + 1] = t1; o2[ra + 2] = t2; o2[ra + 3] = t3;
                o2[rb + 0] = t4; o2[rb + 1] = t5; o2[rb + 2] = t6; o2[rb + 3] = t7;
            }
        }
        __syncthreads();
        p ^= 1;
    }
}

// =================== fallback (round-2 kernel, proven) =====================
typedef _Float16 half2_t __attribute__((ext_vector_type(2)));
__device__ __forceinline__ float dot2f(uint32_t w, uint32_t h, float acc) {
    return __builtin_amdgcn_fdot2(__builtin_bit_cast(half2_t, w),
                                  __builtin_bit_cast(half2_t, h), acc, false);
}
__device__ __forceinline__ uint32_t pack2(float a, float b) {
    half2_t h; h[0] = (_Float16)a; h[1] = (_Float16)b;
    return __builtin_bit_cast(uint32_t, h);
}
template<int CTRL>
__device__ __forceinline__ float dpp_sum(float x) {
    int xi = __builtin_bit_cast(int, x);
    int yi = __builtin_amdgcn_mov_dpp(xi, CTRL, 0xF, 0xF, true);
    return x + __builtin_bit_cast(float, yi);
}
__device__ __forceinline__ float swz4_sum(float x) {
    int xi = __builtin_bit_cast(int, x);
    int yi = __builtin_amdgcn_ds_swizzle(xi, 0x101F);
    return x + __builtin_bit_cast(float, yi);
}
struct SmemFB {
    uint4     wl[16][512];
    _Float16  hbuf[2][8][72];
};
#define FB_DOT4(accv, wrow, hc) \
    accv = dot2f((wrow)[0], hc.x, accv); accv = dot2f((wrow)[1], hc.y, accv); \
    accv = dot2f((wrow)[2], hc.z, accv); accv = dot2f((wrow)[3], hc.w, accv);

__global__ __launch_bounds__(512, 2)
void rnn_ksplit_kernel(const float* __restrict__ x, const float* __restrict__ h0,
                       const float* __restrict__ W_ih, const float* __restrict__ W_hh,
                       const float* __restrict__ b_ih, const float* __restrict__ b_hh,
                       float* __restrict__ out)
{
    __shared__ SmemFB sm;
    const int t = threadIdx.x;
    const int b = blockIdx.x;
    const int s = t & 7;
    const int rbase = t & ~7;

    uint32_t wreg[6][32];
    #pragma unroll
    for (int j = 0; j < 6; ++j) {
        const float* wr = W_hh + (size_t)(rbase + j) * HID + s * 64;
        #pragma unroll
        for (int q = 0; q < 16; ++q) {
            float4 v4 = ((const float4*)wr)[q];
            wreg[j][2*q]   = pack2(v4.x, v4.y);
            wreg[j][2*q+1] = pack2(v4.z, v4.w);
        }
    }
    #pragma unroll
    for (int v = 0; v < 2; ++v) {
        const float* wr = W_hh + (size_t)(rbase + 6 + v) * HID + s * 64;
        #pragma unroll
        for (int cc = 0; cc < 8; ++cc) {
            float4 aa = ((const float4*)wr)[2*cc];
            float4 bb2 = ((const float4*)wr)[2*cc+1];
            uint4 wv2;
            wv2.x = pack2(aa.x, aa.y); wv2.y = pack2(aa.z, aa.w);
            wv2.z = pack2(bb2.x, bb2.y); wv2.w = pack2(bb2.z, bb2.w);
            sm.wl[v*8 + cc][t] = wv2;
        }
    }
    uint32_t wih[8][4];
    #pragma unroll
    for (int j = 0; j < 8; ++j) {
        const float* wr = W_ih + (size_t)(rbase + j) * INDIM + s * 8;
        float4 aa = ((const float4*)wr)[0];
        float4 bb2 = ((const float4*)wr)[1];
        wih[j][0] = pack2(aa.x, aa.y); wih[j][1] = pack2(aa.z, aa.w);
        wih[j][2] = pack2(bb2.x, bb2.y); wih[j][3] = pack2(bb2.z, bb2.w);
    }
    const float bsum = b_ih[t] + b_hh[t];
    sm.hbuf[0][t >> 6][t & 63] = (_Float16)h0[(size_t)b * HID + t];
    const float* xbase = x + (size_t)b * SEQ * INDIM + s * 8;
    float4 xa = ((const float4*)xbase)[0];
    float4 xb = ((const float4*)xbase)[1];
    const bool b0 = (s & 1) != 0, b1 = (s & 2) != 0, b2 = (s & 4) != 0;
    __syncthreads();

    float hlast = 0.f;
    #pragma unroll 1
    for (int tt = 0; tt < SEQ; ++tt) {
        const int tn = (tt + 1 < SEQ) ? tt + 1 : tt;
        const float* xpf = xbase + (size_t)tn * INDIM;
        float4 xa_n = ((const float4*)xpf)[0];
        float4 xb_n = ((const float4*)xpf)[1];
        const int par = tt & 1;
        float a0=0,a1=0,a2=0,a3=0,a4=0,a5=0,a6=0,a7=0;
        const uint4* hp = (const uint4*)&sm.hbuf[par][s][0];
        #pragma unroll
        for (int cc = 0; cc < 8; ++cc) {
            uint4 hc = hp[cc];
            uint4 w6 = sm.wl[cc][t];
            uint4 w7 = sm.wl[8 + cc][t];
            FB_DOT4(a0, &wreg[0][4*cc], hc);
            FB_DOT4(a1, &wreg[1][4*cc], hc);
            FB_DOT4(a2, &wreg[2][4*cc], hc);
            FB_DOT4(a3, &wreg[3][4*cc], hc);
            FB_DOT4(a4, &wreg[4][4*cc], hc);
            FB_DOT4(a5, &wreg[5][4*cc], hc);
            a6 = dot2f(w6.x, hc.x, a6); a6 = dot2f(w6.y, hc.y, a6);
            a6 = dot2f(w6.z, hc.z, a6); a6 = dot2f(w6.w, hc.w, a6);
            a7 = dot2f(w7.x, hc.x, a7); a7 = dot2f(w7.y, hc.y, a7);
            a7 = dot2f(w7.z, hc.z, a7); a7 = dot2f(w7.w, hc.w, a7);
        }
        {
            uint32_t xp0 = pack2(xa.x, xa.y), xp1 = pack2(xa.z, xa.w);
            uint32_t xp2 = pack2(xb.x, xb.y), xp3 = pack2(xb.z, xb.w);
            uint4 xc; xc.x = xp0; xc.y = xp1; xc.z = xp2; xc.w = xp3;
            FB_DOT4(a0, wih[0], xc); FB_DOT4(a1, wih[1], xc);
            FB_DOT4(a2, wih[2], xc); FB_DOT4(a3, wih[3], xc);
            FB_DOT4(a4, wih[4], xc); FB_DOT4(a5, wih[5], xc);
            FB_DOT4(a6, wih[6], xc); FB_DOT4(a7, wih[7], xc);
        }
        float t0 = dpp_sum<0xB1>(a0), u0 = dpp_sum<0xB1>(a1);
        float t1 = dpp_sum<0xB1>(a2), u1 = dpp_sum<0xB1>(a3);
        float t2 = dpp_sum<0xB1>(a4), u2 = dpp_sum<0xB1>(a5);
        float t3 = dpp_sum<0xB1>(a6), u3 = dpp_sum<0xB1>(a7);
        float q0 = b0 ? u0 : t0;
        float q1 = b0 ? u1 : t1;
        float q2 = b0 ? u2 : t2;
        float q3 = b0 ? u3 : t3;
        float r0a = dpp_sum<0x4E>(q0), r0b = dpp_sum<0x4E>(q1);
        float r1a = dpp_sum<0x4E>(q2), r1b = dpp_sum<0x4E>(q3);
        float r0 = b1 ? r0b : r0a;
        float r1 = b1 ? r1b : r1a;
        float f0 = swz4_sum(r0), f1 = swz4_sum(r1);
        float accv = (b2 ? f1 : f0) + bsum;
        float e  = __expf(2.0f * accv);
        float th = 1.0f - 2.0f * __builtin_amdgcn_rcpf(e + 1.0f);
        sm.hbuf[1 - par][t >> 6][t & 63] = (_Float16)th;
        hlast = th;
        xa = xa_n; xb = xb_n;
        __syncthreads();
    }
    out[(size_t)b * HID + t] = hlast;
    out[(size_t)BATCH * HID + (size_t)b * HID + t] = hlast;
}

extern "C" void kernel_launch(void* const* d_in, const int* in_sizes, int n_in,
                              void* d_out, int out_size, void* d_ws, size_t ws_size,
                              hipStream_t stream) {
    (void)in_sizes; (void)n_in; (void)out_size;
    const float* x    = (const float*)d_in[0];
    const float* h0   = (const float*)d_in[1];
    const float* W_ih = (const float*)d_in[2];
    const float* W_hh = (const float*)d_in[3];
    const float* b_ih = (const float*)d_in[4];
    const float* b_hh = (const float*)d_in[5];
    float* out = (float*)d_out;

    if (ws_size >= WS_NEED) {
        f16* xp  = (f16*)d_ws;
        f16* wsc = (f16*)((char*)d_ws + XP_BYTES);
        hipLaunchKernelGGL(wconv_kernel, dim3(16), dim3(256), 0, stream, W_hh, wsc);
        hipLaunchKernelGGL(xp_gemm_kernel, dim3(16, 16), dim3(256), 0, stream,
                           x, W_ih, b_ih, b_hh, xp);
        hipLaunchKernelGGL(rnn_mfma_kernel, dim3(16), dim3(256), 0, stream,
                           h0, W_hh, xp, wsc, out);
    } else {
        hipLaunchKernelGGL(rnn_ksplit_kernel, dim3(BATCH), dim3(512), 0, stream,
                           x, h0, W_ih, W_hh, b_ih, b_hh, out);
    }
}

// Round 6
// 1849.115 us; speedup vs baseline: 2.9640x; 1.4213x over previous
//
#include <hip/hip_runtime.h>
#include <stdint.h>

#define BATCH 256
#define SEQ   512
#define INDIM 64
#define HID   512

typedef _Float16 f16;
typedef _Float16 f16x2 __attribute__((ext_vector_type(2)));
typedef _Float16 f16x8 __attribute__((ext_vector_type(8)));
typedef float    f32x4 __attribute__((ext_vector_type(4)));

#define XP_BYTES  134217728ULL            // 16 blk * 512 s * 32 tiles * 64 lanes * 8 B
#define WSC_BYTES 262144ULL               // 8 kappa * 32 tiles * 64 lanes * 16 B
#define WS_NEED   (XP_BYTES + WSC_BYTES)

// Row permutation making D-layout -> next-step B-frag conversion lane-local.
// wv in [0,8), rho in [0,4), m in [0,16).  (validated algebra, re-based to 64 rows/wave)
__device__ __forceinline__ int row_of8(int wv, int rho, int m) {
    return wv*64 + (rho>>1)*32 + (m>>2)*8 + (rho&1)*4 + (m&3);
}
__device__ __forceinline__ f16x2 pkrtz(float a, float b) {
    return __builtin_bit_cast(f16x2, __builtin_amdgcn_cvt_pkrtz(a, b));
}
union FU { f16x8 v; f16x2 h2[4]; uint32_t u[4]; };
__device__ __forceinline__ f16x8 pack8(float4 a, float4 b) {
    FU r;
    r.h2[0] = pkrtz(a.x, a.y); r.h2[1] = pkrtz(a.z, a.w);
    r.h2[2] = pkrtz(b.x, b.y); r.h2[3] = pkrtz(b.z, b.w);
    return r.v;
}
__device__ __forceinline__ float fast_tanh(float x) {
    float e = __expf(2.0f * x);
    return 1.0f - 2.0f * __builtin_amdgcn_rcpf(e + 1.0f);
}
__device__ __forceinline__ f32x4 mfma16(f16x8 a, f16x8 b, f32x4 c) {
    return __builtin_amdgcn_mfma_f32_16x16x32_f16(a, b, c, 0, 0, 0);
}

// ---- sidecar: W_hh kappa 8..15 as f16 A-frags (L2-resident, re-read each step) ----
__global__ void wconv_kernel(const float* __restrict__ W_hh, f16* __restrict__ wsc)
{
    int id = blockIdx.x * 256 + threadIdx.x;      // 0 .. 16383
    if (id >= 8*32*64) return;
    int l = id & 63, tau = (id >> 6) & 31, ks = id >> 11;    // ks: kappa-8
    int wv = tau >> 2, rho = tau & 3, g = l >> 4, c = l & 15;
    const float* p = W_hh + (size_t)row_of8(wv, rho, c) * HID + (8 + ks) * 32 + g * 8;
    f16x8 v = pack8(((const float4*)p)[0], ((const float4*)p)[1]);
    *(f16x8*)(wsc + (size_t)id * 8) = v;
}

// ---- xp = x @ W_ih^T + b_ih + b_hh, stored f16 in D-frag layout ----
__global__ __launch_bounds__(256)
void xp_gemm_kernel(const float* __restrict__ x, const float* __restrict__ W_ih,
                    const float* __restrict__ b_ih, const float* __restrict__ b_hh,
                    f16* __restrict__ xp)
{
    const int t = threadIdx.x, w = t >> 6, l = t & 63, g = l >> 4, c = l & 15;
    const int bb = blockIdx.x;          // batch block 0..15
    const int sc = blockIdx.y;          // s chunk 0..15 (32 s each)

    f16x8 wf[8][2];
    float bias[8][4];
    #pragma unroll
    for (int j = 0; j < 8; ++j) {
        const int tau = w * 8 + j, wv = tau >> 2, rho = tau & 3;
        const float* pr = W_ih + (size_t)row_of8(wv, rho, c) * INDIM;
        #pragma unroll
        for (int kx = 0; kx < 2; ++kx) {
            const float* p4 = pr + kx * 32 + g * 8;
            wf[j][kx] = pack8(((const float4*)p4)[0], ((const float4*)p4)[1]);
        }
        #pragma unroll
        for (int r = 0; r < 4; ++r) {
            int row = row_of8(wv, rho, 4 * g + r);
            bias[j][r] = b_ih[row] + b_hh[row];
        }
    }

    const float* xb = x + (size_t)(bb * 16 + c) * SEQ * INDIM;
    #pragma unroll 1
    for (int si = 0; si < 32; ++si) {
        const int s = sc * 32 + si;
        const float* xs = xb + (size_t)s * INDIM;
        f16x8 bx[2];
        #pragma unroll
        for (int kx = 0; kx < 2; ++kx) {
            const float* p4 = xs + kx * 32 + g * 8;
            bx[kx] = pack8(((const float4*)p4)[0], ((const float4*)p4)[1]);
        }
        #pragma unroll
        for (int j = 0; j < 8; ++j) {
            f32x4 acc; acc[0] = bias[j][0]; acc[1] = bias[j][1];
            acc[2] = bias[j][2]; acc[3] = bias[j][3];
            acc = mfma16(wf[j][0], bx[0], acc);
            acc = mfma16(wf[j][1], bx[1], acc);
            f16x2 lo = pkrtz(acc[0], acc[1]), hi = pkrtz(acc[2], acc[3]);
            uint2 st;
            st.x = __builtin_bit_cast(uint32_t, lo);
            st.y = __builtin_bit_cast(uint32_t, hi);
            size_t idx = (((size_t)bb * SEQ + s) * 32 + w * 8 + j) * 64 + l;
            *(uint2*)(xp + idx * 4) = st;
        }
    }
}

// ---- persistent recurrent kernel: 16 blocks x 512 thr (8 waves, 2/SIMD) ----
__global__ __launch_bounds__(512, 2)
void rnn_mfma8_kernel(const float* __restrict__ h0, const float* __restrict__ W_hh,
                      const f16* __restrict__ xp, const f16* __restrict__ wsc,
                      float* __restrict__ out)
{
    __shared__ f16x8 s_hbuf[2][16 * 64];   // 32 KB: h frag double buffer
    const int t = threadIdx.x, wv = t >> 6, l = t & 63, g = l >> 4, c = l & 15;
    const int bb = blockIdx.x;

    // W_hh kappa 0..7 into registers (A-frag layout, permuted rows): 128 VGPRs
    f16x8 wreg[8][4];
    #pragma unroll
    for (int kk = 0; kk < 8; ++kk)
        #pragma unroll
        for (int rho = 0; rho < 4; ++rho) {
            const float* p4 = W_hh + (size_t)row_of8(wv, rho, c) * HID + kk * 32 + g * 8;
            wreg[kk][rho] = pack8(((const float4*)p4)[0], ((const float4*)p4)[1]);
        }

    // h0: each wave writes its own 2 kappa frags (kappa = 2wv, 2wv+1)
    #pragma unroll
    for (int P = 0; P < 2; ++P) {
        const int kap = 2 * wv + P;
        const float* p4 = h0 + (size_t)(bb * 16 + c) * HID + kap * 32 + g * 8;
        s_hbuf[0][kap * 64 + l] = pack8(((const float4*)p4)[0], ((const float4*)p4)[1]);
    }

    // xp prefetch for step 0
    uint2 xn[4];
    #pragma unroll
    for (int rho = 0; rho < 4; ++rho)
        xn[rho] = *(const uint2*)(xp + ((((size_t)bb * SEQ) * 32 + wv * 4 + rho) * 64 + l) * 4);

    const f16x8* wsb = (const f16x8*)wsc;

#define SLOAD(BUF, KS) { \
        const f16x8* _b = wsb + ((size_t)(KS) * 32 + wv * 4) * 64 + l; \
        BUF[0] = _b[0]; BUF[1] = _b[64]; BUF[2] = _b[128]; BUF[3] = _b[192]; }
#define SUSE(BUF, KAP) { \
        f16x8 bf = hb[(KAP) * 64 + l]; \
        acc[0] = mfma16(BUF[0], bf, acc[0]); \
        acc[1] = mfma16(BUF[1], bf, acc[1]); \
        acc[2] = mfma16(BUF[2], bf, acc[2]); \
        acc[3] = mfma16(BUF[3], bf, acc[3]); }
#define RUSE(KK) { \
        f16x8 bf = hb[(KK) * 64 + l]; \
        acc[0] = mfma16(wreg[KK][0], bf, acc[0]); \
        acc[1] = mfma16(wreg[KK][1], bf, acc[1]); \
        acc[2] = mfma16(wreg[KK][2], bf, acc[2]); \
        acc[3] = mfma16(wreg[KK][3], bf, acc[3]); }

    // sidecar prologue: kappa 8..11 in flight
    f16x8 sA[4], sB[4], sC[4], sD[4];
    SLOAD(sA, 0) SLOAD(sB, 1) SLOAD(sC, 2) SLOAD(sD, 3)

    __syncthreads();

    int p = 0;
    #pragma unroll 1
    for (int tt = 0; tt < SEQ; ++tt) {
        // acc init from xp (f16 -> f32)
        f32x4 acc[4];
        #pragma unroll
        for (int rho = 0; rho < 4; ++rho) {
            f16x2 lo = __builtin_bit_cast(f16x2, xn[rho].x);
            f16x2 hi = __builtin_bit_cast(f16x2, xn[rho].y);
            f32x4 a; a[0] = (float)lo[0]; a[1] = (float)lo[1];
            a[2] = (float)hi[0]; a[3] = (float)hi[1];
            acc[rho] = a;
        }
        // xp prefetch for next step (clamped; branchless)
        {
            const int tn = (tt + 1 < SEQ) ? tt + 1 : SEQ - 1;
            #pragma unroll
            for (int rho = 0; rho < 4; ++rho)
                xn[rho] = *(const uint2*)(xp +
                    ((((size_t)bb * SEQ + tn) * 32 + wv * 4 + rho) * 64 + l) * 4);
        }

        const f16x8* hb = &s_hbuf[p][0];

        // kappa 0..7 from registers
        RUSE(0) RUSE(1) RUSE(2) RUSE(3) RUSE(4) RUSE(5) RUSE(6) RUSE(7)

        // kappa 8..15 streamed from L2; cyclic refill 4 ahead (addresses constant over t)
        SUSE(sA,  8) SLOAD(sA, 4)      // refill kappa 12
        SUSE(sB,  9) SLOAD(sB, 5)
        SUSE(sC, 10) SLOAD(sC, 6)
        SUSE(sD, 11) SLOAD(sD, 7)
        SUSE(sA, 12) SLOAD(sA, 0)      // refill kappa 8 (next step)
        SUSE(sB, 13) SLOAD(sB, 1)
        SUSE(sC, 14) SLOAD(sC, 2)
        SUSE(sD, 15) SLOAD(sD, 3)

        // tanh -> pack (lane-local) -> own B-frags for next step
        f16x8* hw = &s_hbuf[1 - p][0];
        #pragma unroll
        for (int P = 0; P < 2; ++P) {
            float t0 = fast_tanh(acc[2*P][0]),   t1 = fast_tanh(acc[2*P][1]);
            float t2 = fast_tanh(acc[2*P][2]),   t3 = fast_tanh(acc[2*P][3]);
            float t4 = fast_tanh(acc[2*P+1][0]), t5 = fast_tanh(acc[2*P+1][1]);
            float t6 = fast_tanh(acc[2*P+1][2]), t7 = fast_tanh(acc[2*P+1][3]);
            FU fu;
            fu.h2[0] = pkrtz(t0, t1); fu.h2[1] = pkrtz(t2, t3);
            fu.h2[2] = pkrtz(t4, t5); fu.h2[3] = pkrtz(t6, t7);
            hw[(2 * wv + P) * 64 + l] = fu.v;
            if (tt == SEQ - 1) {
                float* ob = out + (size_t)(bb * 16 + c) * HID;
                float* o2 = ob + (size_t)BATCH * HID;
                int ra = row_of8(wv, 2 * P, 4 * g);      // rows ra..ra+3 = t0..t3
                int rb = ra + 4;                          // rows rb..rb+3 = t4..t7
                ob[ra + 0] = t0; ob[ra + 1] = t1; ob[ra + 2] = t2; ob[ra + 3] = t3;
                ob[rb + 0] = t4; ob[rb + 1] = t5; ob[rb + 2] = t6; ob[rb + 3] = t7;
                o2[ra + 0] = t0; o2[ra + 1] = t1; o2[ra + 2] = t2; o2[ra + 3] = t3;
                o2[rb + 0] = t4; o2[rb + 1] = t5; o2[rb + 2] = t6; o2[rb + 3] = t7;
            }
        }

        // step barrier: drain LDS writes only; keep sidecar/global loads in flight
        asm volatile("s_waitcnt lgkmcnt(0)" ::: "memory");
        __builtin_amdgcn_s_barrier();
        asm volatile("" ::: "memory");
        p ^= 1;
    }
#undef SLOAD
#undef SUSE
#undef RUSE
}

// =================== fallback (round-2 kernel, proven 962 us) ===============
typedef _Float16 half2_t __attribute__((ext_vector_type(2)));
__device__ __forceinline__ float dot2f(uint32_t w, uint32_t h, float acc) {
    return __builtin_amdgcn_fdot2(__builtin_bit_cast(half2_t, w),
                                  __builtin_bit_cast(half2_t, h), acc, false);
}
__device__ __forceinline__ uint32_t pack2(float a, float b) {
    half2_t h; h[0] = (_Float16)a; h[1] = (_Float16)b;
    return __builtin_bit_cast(uint32_t, h);
}
template<int CTRL>
__device__ __forceinline__ float dpp_sum(float x) {
    int xi = __builtin_bit_cast(int, x);
    int yi = __builtin_amdgcn_mov_dpp(xi, CTRL, 0xF, 0xF, true);
    return x + __builtin_bit_cast(float, yi);
}
__device__ __forceinline__ float swz4_sum(float x) {
    int xi = __builtin_bit_cast(int, x);
    int yi = __builtin_amdgcn_ds_swizzle(xi, 0x101F);
    return x + __builtin_bit_cast(float, yi);
}
struct SmemFB {
    uint4     wl[16][512];
    _Float16  hbuf[2][8][72];
};
#define FB_DOT4(accv, wrow, hc) \
    accv = dot2f((wrow)[0], hc.x, accv); accv = dot2f((wrow)[1], hc.y, accv); \
    accv = dot2f((wrow)[2], hc.z, accv); accv = dot2f((wrow)[3], hc.w, accv);

__global__ __launch_bounds__(512, 2)
void rnn_ksplit_kernel(const float* __restrict__ x, const float* __restrict__ h0,
                       const float* __restrict__ W_ih, const float* __restrict__ W_hh,
                       const float* __restrict__ b_ih, const float* __restrict__ b_hh,
                       float* __restrict__ out)
{
    __shared__ SmemFB sm;
    const int t = threadIdx.x;
    const int b = blockIdx.x;
    const int s = t & 7;
    const int rbase = t & ~7;

    uint32_t wreg[6][32];
    #pragma unroll
    for (int j = 0; j < 6; ++j) {
        const float* wr = W_hh + (size_t)(rbase + j) * HID + s * 64;
        #pragma unroll
        for (int q = 0; q < 16; ++q) {
            float4 v4 = ((const float4*)wr)[q];
            wreg[j][2*q]   = pack2(v4.x, v4.y);
            wreg[j][2*q+1] = pack2(v4.z, v4.w);
        }
    }
    #pragma unroll
    for (int v = 0; v < 2; ++v) {
        const float* wr = W_hh + (size_t)(rbase + 6 + v) * HID + s * 64;
        #pragma unroll
        for (int cc = 0; cc < 8; ++cc) {
            float4 aa = ((const float4*)wr)[2*cc];
            float4 bb2 = ((const float4*)wr)[2*cc+1];
            uint4 wv2;
            wv2.x = pack2(aa.x, aa.y); wv2.y = pack2(aa.z, aa.w);
            wv2.z = pack2(bb2.x, bb2.y); wv2.w = pack2(bb2.z, bb2.w);
            sm.wl[v*8 + cc][t] = wv2;
        }
    }
    uint32_t wih[8][4];
    #pragma unroll
    for (int j = 0; j < 8; ++j) {
        const float* wr = W_ih + (size_t)(rbase + j) * INDIM + s * 8;
        float4 aa = ((const float4*)wr)[0];
        float4 bb2 = ((const float4*)wr)[1];
        wih[j][0] = pack2(aa.x, aa.y); wih[j][1] = pack2(aa.z, aa.w);
        wih[j][2] = pack2(bb2.x, bb2.y); wih[j][3] = pack2(bb2.z, bb2.w);
    }
    const float bsum = b_ih[t] + b_hh[t];
    sm.hbuf[0][t >> 6][t & 63] = (_Float16)h0[(size_t)b * HID + t];
    const float* xbase = x + (size_t)b * SEQ * INDIM + s * 8;
    float4 xa = ((const float4*)xbase)[0];
    float4 xb = ((const float4*)xbase)[1];
    const bool b0 = (s & 1) != 0, b1 = (s & 2) != 0, b2 = (s & 4) != 0;
    __syncthreads();

    float hlast = 0.f;
    #pragma unroll 1
    for (int tt = 0; tt < SEQ; ++tt) {
        const int tn = (tt + 1 < SEQ) ? tt + 1 : tt;
        const float* xpf = xbase + (size_t)tn * INDIM;
        float4 xa_n = ((const float4*)xpf)[0];
        float4 xb_n = ((const float4*)xpf)[1];
        const int par = tt & 1;
        float a0=0,a1=0,a2=0,a3=0,a4=0,a5=0,a6=0,a7=0;
        const uint4* hp = (const uint4*)&sm.hbuf[par][s][0];
        #pragma unroll
        for (int cc = 0; cc < 8; ++cc) {
            uint4 hc = hp[cc];
            uint4 w6 = sm.wl[cc][t];
            uint4 w7 = sm.wl[8 + cc][t];
            FB_DOT4(a0, &wreg[0][4*cc], hc);
            FB_DOT4(a1, &wreg[1][4*cc], hc);
            FB_DOT4(a2, &wreg[2][4*cc], hc);
            FB_DOT4(a3, &wreg[3][4*cc], hc);
            FB_DOT4(a4, &wreg[4][4*cc], hc);
            FB_DOT4(a5, &wreg[5][4*cc], hc);
            a6 = dot2f(w6.x, hc.x, a6); a6 = dot2f(w6.y, hc.y, a6);
            a6 = dot2f(w6.z, hc.z, a6); a6 = dot2f(w6.w, hc.w, a6);
            a7 = dot2f(w7.x, hc.x, a7); a7 = dot2f(w7.y, hc.y, a7);
            a7 = dot2f(w7.z, hc.z, a7); a7 = dot2f(w7.w, hc.w, a7);
        }
        {
            uint32_t xp0 = pack2(xa.x, xa.y), xp1 = pack2(xa.z, xa.w);
            uint32_t xp2 = pack2(xb.x, xb.y), xp3 = pack2(xb.z, xb.w);
            uint4 xc; xc.x = xp0; xc.y = xp1; xc.z = xp2; xc.w = xp3;
            FB_DOT4(a0, wih[0], xc); FB_DOT4(a1, wih[1], xc);
            FB_DOT4(a2, wih[2], xc); FB_DOT4(a3, wih[3], xc);
            FB_DOT4(a4, wih[4], xc); FB_DOT4(a5, wih[5], xc);
            FB_DOT4(a6, wih[6], xc); FB_DOT4(a7, wih[7], xc);
        }
        float t0 = dpp_sum<0xB1>(a0), u0 = dpp_sum<0xB1>(a1);
        float t1 = dpp_sum<0xB1>(a2), u1 = dpp_sum<0xB1>(a3);
        float t2 = dpp_sum<0xB1>(a4), u2 = dpp_sum<0xB1>(a5);
        float t3 = dpp_sum<0xB1>(a6), u3 = dpp_sum<0xB1>(a7);
        float q0 = b0 ? u0 : t0;
        float q1 = b0 ? u1 : t1;
        float q2 = b0 ? u2 : t2;
        float q3 = b0 ? u3 : t3;
        float r0a = dpp_sum<0x4E>(q0), r0b = dpp_sum<0x4E>(q1);
        float r1a = dpp_sum<0x4E>(q2), r1b = dpp_sum<0x4E>(q3);
        float r0 = b1 ? r0b : r0a;
        float r1 = b1 ? r1b : r1a;
        float f0 = swz4_sum(r0), f1 = swz4_sum(r1);
        float accv = (b2 ? f1 : f0) + bsum;
        float e  = __expf(2.0f * accv);
        float th = 1.0f - 2.0f * __builtin_amdgcn_rcpf(e + 1.0f);
        sm.hbuf[1 - par][t >> 6][t & 63] = (_Float16)th;
        hlast = th;
        xa = xa_n; xb = xb_n;
        __syncthreads();
    }
    out[(size_t)b * HID + t] = hlast;
    out[(size_t)BATCH * HID + (size_t)b * HID + t] = hlast;
}

extern "C" void kernel_launch(void* const* d_in, const int* in_sizes, int n_in,
                              void* d_out, int out_size, void* d_ws, size_t ws_size,
                              hipStream_t stream) {
    (void)in_sizes; (void)n_in; (void)out_size;
    const float* x    = (const float*)d_in[0];
    const float* h0   = (const float*)d_in[1];
    const float* W_ih = (const float*)d_in[2];
    const float* W_hh = (const float*)d_in[3];
    const float* b_ih = (const float*)d_in[4];
    const float* b_hh = (const float*)d_in[5];
    float* out = (float*)d_out;

    if (ws_size >= WS_NEED) {
        f16* xp  = (f16*)d_ws;
        f16* wsc = (f16*)((char*)d_ws + XP_BYTES);
        hipLaunchKernelGGL(wconv_kernel, dim3(64), dim3(256), 0, stream, W_hh, wsc);
        hipLaunchKernelGGL(xp_gemm_kernel, dim3(16, 16), dim3(256), 0, stream,
                           x, W_ih, b_ih, b_hh, xp);
        hipLaunchKernelGGL(rnn_mfma8_kernel, dim3(16), dim3(512), 0, stream,
                           h0, W_hh, xp, wsc, out);
    } else {
        hipLaunchKernelGGL(rnn_ksplit_kernel, dim3(BATCH), dim3(512), 0, stream,
                           x, h0, W_ih, W_hh, b_ih, b_hh, out);
    }
}